// Round 1
// baseline (564.149 us; speedup 1.0000x reference)
//
#include <hip/hip_runtime.h>
#include <cstddef>

#define NS 64000

// ---------------- ws layout (in floats) ----------------
// W0:  8*192*192 = 294912
// B0:  8*192     = 1536
// W1:  8*256*256 = 524288   (complex-folded [[Wr,-Wi],[Wi,Wr]])
// W2:  8*128*128 = 131072
// X0:  NS*192, X1: NS*256, X2: NS*128
// Y0:  NS*192, Y1: NS*256, Y2: NS*128
static const size_t OFF_W0 = 0;
static const size_t OFF_B0 = OFF_W0 + 294912;
static const size_t OFF_W1 = OFF_B0 + 1536;
static const size_t OFF_W2 = OFF_W1 + 524288;
static const size_t OFF_X0 = OFF_W2 + 131072;
static const size_t OFF_X1 = OFF_X0 + (size_t)NS * 192;
static const size_t OFF_X2 = OFF_X1 + (size_t)NS * 256;
static const size_t OFF_Y0 = OFF_X2 + (size_t)NS * 128;
static const size_t OFF_Y1 = OFF_Y0 + (size_t)NS * 192;
static const size_t OFF_Y2 = OFF_Y1 + (size_t)NS * 256;
// total = 74,679,808 floats = ~285 MiB

// ---------------- expert-mix kernel ----------------
__global__ __launch_bounds__(256) void mix_kernel(
    const float* __restrict__ coef,
    const float* __restrict__ w_m0, const float* __restrict__ b_m0,
    const float* __restrict__ ws_m0, const float* __restrict__ bs_m0,
    const float* __restrict__ w_m1, const float* __restrict__ ws_m1,
    const float* __restrict__ w_m2, const float* __restrict__ ws_m2,
    float* __restrict__ W0, float* __restrict__ B0,
    float* __restrict__ W1, float* __restrict__ W2)
{
    int tid = blockIdx.x * 256 + threadIdx.x;
    if (tid < 294912) {
        // W0[b, o, i] = sum_e coef[b,e] w_m0[e,o,i] + ws_m0[o,i]
        int b = tid / 36864, rem = tid % 36864;
        float s = ws_m0[rem];
        #pragma unroll
        for (int e = 0; e < 8; e++) s += coef[b * 8 + e] * w_m0[e * 36864 + rem];
        W0[tid] = s;
    } else if (tid < 296448) {
        int i2 = tid - 294912;
        int b = i2 / 192, o = i2 % 192;
        float s = bs_m0[o];
        #pragma unroll
        for (int e = 0; e < 8; e++) s += coef[b * 8 + e] * b_m0[e * 192 + o];
        B0[i2] = s;
    } else if (tid < 820736) {
        // W1big[b, o, i] (256x256) from mixed w_m1 (256x128): Wr = rows 0..127, Wi = rows 128..255
        // row o<128:  [ Wr[o] | -Wi[o] ] ; row 128+o: [ Wi[o] | Wr[o] ]
        int i3 = tid - 296448;
        int b = i3 >> 16, rem = i3 & 65535;
        int o = rem >> 8, i = rem & 255;
        int r, cc; float sign = 1.0f;
        if (o < 128) { if (i < 128) { r = o;       cc = i; } else { r = 128 + o;      cc = i - 128; sign = -1.0f; } }
        else { int o2 = o - 128; if (i < 128) { r = 128 + o2; cc = i; } else { r = o2; cc = i - 128; } }
        int idx = r * 128 + cc;
        float s = ws_m1[idx];
        #pragma unroll
        for (int e = 0; e < 8; e++) s += coef[b * 8 + e] * w_m1[e * 32768 + idx];
        W1[i3] = sign * s;
    } else if (tid < 951808) {
        int i4 = tid - 820736;
        int b = i4 >> 14, rem = i4 & 16383;
        int o = rem >> 7, i = rem & 127;
        int r, cc; float sign = 1.0f;
        if (o < 64) { if (i < 64) { r = o;      cc = i; } else { r = 64 + o;      cc = i - 64; sign = -1.0f; } }
        else { int o2 = o - 64; if (i < 64) { r = 64 + o2; cc = i; } else { r = o2; cc = i - 64; } }
        int idx = r * 64 + cc;
        float s = ws_m2[idx];
        #pragma unroll
        for (int e = 0; e < 8; e++) s += coef[b * 8 + e] * w_m2[e * 8192 + idx];
        W2[i4] = sign * s;
    }
}

// ---------------- rotation helpers ----------------
__device__ __forceinline__ void zrot1(float& v0, float& v2, float c, float s) {
    float t0 = c * v0 + s * v2;
    v2 = -s * v0 + c * v2;
    v0 = t0;
}
__device__ __forceinline__ void j1mul(const float* J, float& v0, float& v1, float& v2) {
    float w0 = J[0] * v0 + J[1] * v1 + J[2] * v2;
    float w1 = J[3] * v0 + J[4] * v1 + J[5] * v2;
    float w2 = J[6] * v0 + J[7] * v1 + J[8] * v2;
    v0 = w0; v1 = w1; v2 = w2;
}
__device__ __forceinline__ void zrot2(float& u0, float& u1, float& u3, float& u4,
                                      float c1, float s1, float c2, float s2) {
    float t0 = c2 * u0 + s2 * u4;
    u4 = -s2 * u0 + c2 * u4;
    u0 = t0;
    float t1 = c1 * u1 + s1 * u3;
    u3 = -s1 * u1 + c1 * u3;
    u1 = t1;
}
__device__ __forceinline__ void j2mul(const float* J, float& u0, float& u1, float& u2, float& u3, float& u4) {
    float w0 = J[0]  * u0 + J[1]  * u1 + J[2]  * u2 + J[3]  * u3 + J[4]  * u4;
    float w1 = J[5]  * u0 + J[6]  * u1 + J[7]  * u2 + J[8]  * u3 + J[9]  * u4;
    float w2 = J[10] * u0 + J[11] * u1 + J[12] * u2 + J[13] * u3 + J[14] * u4;
    float w3 = J[15] * u0 + J[16] * u1 + J[17] * u2 + J[18] * u3 + J[19] * u4;
    float w4 = J[20] * u0 + J[21] * u1 + J[22] * u2 + J[23] * u3 + J[24] * u4;
    u0 = w0; u1 = w1; u2 = w2; u3 = w3; u4 = w4;
}

// ---------------- forward rotate + gather to GEMM layouts ----------------
// one thread per (sample n, channel c); block = 4 samples x 64 channels
__global__ __launch_bounds__(256) void rotate_fwd(
    const float* __restrict__ x,
    const float* __restrict__ alpha, const float* __restrict__ beta, const float* __restrict__ gamma_,
    const float* __restrict__ Jd1, const float* __restrict__ Jd2,
    float* __restrict__ X0, float* __restrict__ X1, float* __restrict__ X2)
{
    int t = threadIdx.x;
    int n = blockIdx.x * 4 + (t >> 6);
    int c = t & 63;
    const float* xr = x + (size_t)n * 576;
    float a = alpha[n], b = beta[n], g = gamma_[n];
    float sa, ca, sb, cb, sg, cg;
    __sincosf(a, &sa, &ca);
    __sincosf(b, &sb, &cb);
    __sincosf(g, &sg, &cg);
    float s2a = 2.f * sa * ca, c2a = ca * ca - sa * sa;
    float s2b = 2.f * sb * cb, c2b = cb * cb - sb * sb;
    float s2g = 2.f * sg * cg, c2g = cg * cg - sg * sg;

    float J1[9], J2[25];
    #pragma unroll
    for (int i = 0; i < 9; i++)  J1[i] = Jd1[i];
    #pragma unroll
    for (int i = 0; i < 25; i++) J2[i] = Jd2[i];

    // ---- l=1: D x = Z(a) J Z(b) J Z(g) x ----
    float v0 = xr[64 + 3 * c], v1 = xr[64 + 3 * c + 1], v2 = xr[64 + 3 * c + 2];
    zrot1(v0, v2, cg, sg);
    j1mul(J1, v0, v1, v2);
    zrot1(v0, v2, cb, sb);
    j1mul(J1, v0, v1, v2);
    zrot1(v0, v2, ca, sa);

    // ---- l=2 ----
    float u0 = xr[256 + 5 * c], u1 = xr[256 + 5 * c + 1], u2 = xr[256 + 5 * c + 2],
          u3 = xr[256 + 5 * c + 3], u4 = xr[256 + 5 * c + 4];
    zrot2(u0, u1, u3, u4, cg, sg, c2g, s2g);
    j2mul(J2, u0, u1, u2, u3, u4);
    zrot2(u0, u1, u3, u4, cb, sb, c2b, s2b);
    j2mul(J2, u0, u1, u2, u3, u4);
    zrot2(u0, u1, u3, u4, ca, sa, c2a, s2a);

    size_t r0 = (size_t)n * 192, r1 = (size_t)n * 256, r2 = (size_t)n * 128;
    // X0 = m=0 features: [l0 c | l1 j1 | l2 j2]
    X0[r0 + c]        = xr[c];
    X0[r0 + 64 + c]   = v1;
    X0[r0 + 128 + c]  = u2;
    // X1 = m=+-1 features: A = [l1 j0 | l2 j1], B = [l1 j2 | l2 j3]
    X1[r1 + c]        = v0;
    X1[r1 + 64 + c]   = u1;
    X1[r1 + 128 + c]  = v2;
    X1[r1 + 192 + c]  = u3;
    // X2 = m=+-2 features: A = l2 j0, B = l2 j4
    X2[r2 + c]        = u0;
    X2[r2 + 64 + c]   = u4;
}

// ---------------- grouped GEMM: Y[n,o] = sum_i X[n,i] * W[g,o,i] (+bias[g,o]) ----------------
// 64x64 tile, 4x4 micro-tile, BK=16, 256 threads. 8000 rows per group (125 tiles, no straddle).
__global__ __launch_bounds__(256) void gemm_kernel(
    const float* __restrict__ X, const float* __restrict__ W,
    const float* __restrict__ bias, float* __restrict__ Y,
    int K, int OUT)
{
    __shared__ float As[16][68];
    __shared__ float Bs[16][68];
    int t = threadIdx.x;
    int m0 = blockIdx.y * 64;
    int n0 = blockIdx.x * 64;
    int g = blockIdx.y / 125;
    const float* Wg = W + (size_t)g * OUT * K;
    int lm = t >> 2;           // 0..63 row within tile (loader)
    int lk = (t & 3) << 2;     // k sub-offset (loader)
    int tx = t & 15, ty = t >> 4;
    float acc[4][4];
    #pragma unroll
    for (int i = 0; i < 4; i++)
        #pragma unroll
        for (int j = 0; j < 4; j++) acc[i][j] = 0.f;

    const float* xp = X + (size_t)(m0 + lm) * K + lk;
    const float* wp = Wg + (size_t)(n0 + lm) * K + lk;

    for (int k0 = 0; k0 < K; k0 += 16) {
        float4 av = *(const float4*)(xp + k0);
        float4 bv = *(const float4*)(wp + k0);
        __syncthreads();
        As[lk + 0][lm] = av.x; As[lk + 1][lm] = av.y; As[lk + 2][lm] = av.z; As[lk + 3][lm] = av.w;
        Bs[lk + 0][lm] = bv.x; Bs[lk + 1][lm] = bv.y; Bs[lk + 2][lm] = bv.z; Bs[lk + 3][lm] = bv.w;
        __syncthreads();
        #pragma unroll
        for (int k = 0; k < 16; k++) {
            float4 a4 = *(const float4*)&As[k][ty << 2];
            float4 b4 = *(const float4*)&Bs[k][tx << 2];
            acc[0][0] += a4.x * b4.x; acc[0][1] += a4.x * b4.y; acc[0][2] += a4.x * b4.z; acc[0][3] += a4.x * b4.w;
            acc[1][0] += a4.y * b4.x; acc[1][1] += a4.y * b4.y; acc[1][2] += a4.y * b4.z; acc[1][3] += a4.y * b4.w;
            acc[2][0] += a4.z * b4.x; acc[2][1] += a4.z * b4.y; acc[2][2] += a4.z * b4.z; acc[2][3] += a4.z * b4.w;
            acc[3][0] += a4.w * b4.x; acc[3][1] += a4.w * b4.y; acc[3][2] += a4.w * b4.z; acc[3][3] += a4.w * b4.w;
        }
    }

    float4 bb = make_float4(0.f, 0.f, 0.f, 0.f);
    if (bias) bb = *(const float4*)&bias[(size_t)g * OUT + n0 + (tx << 2)];
    #pragma unroll
    for (int i = 0; i < 4; i++) {
        int row = m0 + (ty << 2) + i;
        float4 v;
        v.x = acc[i][0] + bb.x;
        v.y = acc[i][1] + bb.y;
        v.z = acc[i][2] + bb.z;
        v.w = acc[i][3] + bb.w;
        *(float4*)&Y[(size_t)row * OUT + n0 + (tx << 2)] = v;
    }
}

// ---------------- inverse rotate + scatter to output ----------------
__global__ __launch_bounds__(256) void rotate_bwd(
    const float* __restrict__ Y0, const float* __restrict__ Y1, const float* __restrict__ Y2,
    const float* __restrict__ alpha, const float* __restrict__ beta, const float* __restrict__ gamma_,
    const float* __restrict__ Jd1, const float* __restrict__ Jd2,
    float* __restrict__ out)
{
    int t = threadIdx.x;
    int n = blockIdx.x * 4 + (t >> 6);
    int c = t & 63;
    float a = alpha[n], b = beta[n], g = gamma_[n];
    float sa, ca, sb, cb, sg, cg;
    __sincosf(a, &sa, &ca);
    __sincosf(b, &sb, &cb);
    __sincosf(g, &sg, &cg);
    // inverse rotation: D' = Z(-g) J Z(-b) J Z(-a); apply Z(-a) first
    sa = -sa; sb = -sb; sg = -sg;
    float s2a = 2.f * sa * ca, c2a = ca * ca - sa * sa;
    float s2b = 2.f * sb * cb, c2b = cb * cb - sb * sb;
    float s2g = 2.f * sg * cg, c2g = cg * cg - sg * sg;

    float J1[9], J2[25];
    #pragma unroll
    for (int i = 0; i < 9; i++)  J1[i] = Jd1[i];
    #pragma unroll
    for (int i = 0; i < 25; i++) J2[i] = Jd2[i];

    size_t r0 = (size_t)n * 192, r1 = (size_t)n * 256, r2 = (size_t)n * 128;
    float* orow = out + (size_t)n * 576;

    // l=0 passthrough
    orow[c] = Y0[r0 + c];

    // l=1: j0 = om1[c] = Y1[c], j1 = Y0[64+c], j2 = op1[c] = Y1[128+c]
    float v0 = Y1[r1 + c], v1 = Y0[r0 + 64 + c], v2 = Y1[r1 + 128 + c];
    zrot1(v0, v2, ca, sa);
    j1mul(J1, v0, v1, v2);
    zrot1(v0, v2, cb, sb);
    j1mul(J1, v0, v1, v2);
    zrot1(v0, v2, cg, sg);
    orow[64 + 3 * c]     = v0;
    orow[64 + 3 * c + 1] = v1;
    orow[64 + 3 * c + 2] = v2;

    // l=2: j0 = om2[c], j1 = om1[64+c], j2 = Y0[128+c], j3 = op1[64+c], j4 = op2[c]
    float u0 = Y2[r2 + c], u1 = Y1[r1 + 64 + c], u2 = Y0[r0 + 128 + c],
          u3 = Y1[r1 + 192 + c], u4 = Y2[r2 + 64 + c];
    zrot2(u0, u1, u3, u4, ca, sa, c2a, s2a);
    j2mul(J2, u0, u1, u2, u3, u4);
    zrot2(u0, u1, u3, u4, cb, sb, c2b, s2b);
    j2mul(J2, u0, u1, u2, u3, u4);
    zrot2(u0, u1, u3, u4, cg, sg, c2g, s2g);
    orow[256 + 5 * c]     = u0;
    orow[256 + 5 * c + 1] = u1;
    orow[256 + 5 * c + 2] = u2;
    orow[256 + 5 * c + 3] = u3;
    orow[256 + 5 * c + 4] = u4;
}

extern "C" void kernel_launch(void* const* d_in, const int* in_sizes, int n_in,
                              void* d_out, int out_size, void* d_ws, size_t ws_size,
                              hipStream_t stream)
{
    const float* x      = (const float*)d_in[0];
    const float* alpha  = (const float*)d_in[1];
    const float* beta   = (const float*)d_in[2];
    const float* gamma_ = (const float*)d_in[3];
    const float* coef   = (const float*)d_in[4];
    const float* Jd1    = (const float*)d_in[5];
    const float* Jd2    = (const float*)d_in[6];
    const float* w_m0   = (const float*)d_in[7];
    const float* b_m0   = (const float*)d_in[8];
    const float* ws_m0  = (const float*)d_in[9];
    const float* bs_m0  = (const float*)d_in[10];
    const float* w_m1   = (const float*)d_in[11];
    const float* ws_m1  = (const float*)d_in[12];
    const float* w_m2   = (const float*)d_in[13];
    const float* ws_m2  = (const float*)d_in[14];

    float* ws = (float*)d_ws;
    float* W0 = ws + OFF_W0;
    float* B0 = ws + OFF_B0;
    float* W1 = ws + OFF_W1;
    float* W2 = ws + OFF_W2;
    float* X0 = ws + OFF_X0;
    float* X1 = ws + OFF_X1;
    float* X2 = ws + OFF_X2;
    float* Y0 = ws + OFF_Y0;
    float* Y1 = ws + OFF_Y1;
    float* Y2 = ws + OFF_Y2;
    float* out = (float*)d_out;

    hipLaunchKernelGGL(mix_kernel, dim3(3718), dim3(256), 0, stream,
                       coef, w_m0, b_m0, ws_m0, bs_m0, w_m1, ws_m1, w_m2, ws_m2,
                       W0, B0, W1, W2);
    hipLaunchKernelGGL(rotate_fwd, dim3(NS / 4), dim3(256), 0, stream,
                       x, alpha, beta, gamma_, Jd1, Jd2, X0, X1, X2);
    hipLaunchKernelGGL(gemm_kernel, dim3(3, NS / 64), dim3(256), 0, stream,
                       X0, W0, B0, Y0, 192, 192);
    hipLaunchKernelGGL(gemm_kernel, dim3(4, NS / 64), dim3(256), 0, stream,
                       X1, W1, (const float*)nullptr, Y1, 256, 256);
    hipLaunchKernelGGL(gemm_kernel, dim3(2, NS / 64), dim3(256), 0, stream,
                       X2, W2, (const float*)nullptr, Y2, 128, 128);
    hipLaunchKernelGGL(rotate_bwd, dim3(NS / 4), dim3(256), 0, stream,
                       Y0, Y1, Y2, alpha, beta, gamma_, Jd1, Jd2, out);
}

// Round 2
// 396.939 us; speedup vs baseline: 1.4212x; 1.4212x over previous
//
#include <hip/hip_runtime.h>
#include <cstddef>

#define NS 64000
#define GROUP 8000
#define GPAD 8192

typedef __bf16 bf16x8 __attribute__((ext_vector_type(8)));
typedef float floatx4 __attribute__((ext_vector_type(4)));
typedef unsigned short ushort_t;

// ---------------- ws layout (bytes) ----------------
static const size_t BY_W0 = 0;                           // 8*192*192*2 = 589824
static const size_t BY_W1 = BY_W0 + 589824;              // 8*256*256*2 = 1048576
static const size_t BY_W2 = BY_W1 + 1048576;             // 8*128*128*2 = 262144
static const size_t BY_B0 = BY_W2 + 262144;              // 8*192*4     = 6144
static const size_t BY_X0 = BY_B0 + 6144;                // 65536*192*2 = 25165824
static const size_t BY_X1 = BY_X0 + 25165824;            // 65536*256*2 = 33554432
static const size_t BY_X2 = BY_X1 + 33554432;            // 65536*128*2 = 16777216
static const size_t BY_Y0 = BY_X2 + 16777216;            // 65536*192*4 = 50331648
static const size_t BY_Y1 = BY_Y0 + 50331648;            // 65536*256*4 = 67108864
static const size_t BY_Y2 = BY_Y1 + 67108864;            // 65536*128*4 = 33554432
// total ~228 MiB

__device__ __forceinline__ unsigned short f2bf(float f) {
    unsigned u = __float_as_uint(f);
    u += 0x7fff + ((u >> 16) & 1);   // round to nearest even
    return (unsigned short)(u >> 16);
}

__device__ __forceinline__ void async_cp16(const void* gsrc, void* ldst) {
    __builtin_amdgcn_global_load_lds(
        (const __attribute__((address_space(1))) unsigned int*)gsrc,
        (__attribute__((address_space(3))) unsigned int*)ldst, 16, 0, 0);
}

// group-padded row index for sample n
__device__ __forceinline__ size_t grow(int n) {
    int g = n / GROUP;
    return (size_t)g * GPAD + (size_t)(n - g * GROUP);
}

// ---------------- expert-mix kernel (bf16 weights out) ----------------
__global__ __launch_bounds__(256) void mix_kernel(
    const float* __restrict__ coef,
    const float* __restrict__ w_m0, const float* __restrict__ b_m0,
    const float* __restrict__ ws_m0, const float* __restrict__ bs_m0,
    const float* __restrict__ w_m1, const float* __restrict__ ws_m1,
    const float* __restrict__ w_m2, const float* __restrict__ ws_m2,
    ushort_t* __restrict__ W0, float* __restrict__ B0,
    ushort_t* __restrict__ W1, ushort_t* __restrict__ W2)
{
    int tid = blockIdx.x * 256 + threadIdx.x;
    if (tid < 294912) {
        int b = tid / 36864, rem = tid % 36864;
        float s = ws_m0[rem];
        #pragma unroll
        for (int e = 0; e < 8; e++) s += coef[b * 8 + e] * w_m0[e * 36864 + rem];
        W0[tid] = f2bf(s);
    } else if (tid < 296448) {
        int i2 = tid - 294912;
        int b = i2 / 192, o = i2 % 192;
        float s = bs_m0[o];
        #pragma unroll
        for (int e = 0; e < 8; e++) s += coef[b * 8 + e] * b_m0[e * 192 + o];
        B0[i2] = s;
    } else if (tid < 820736) {
        // W1big[b,o,i] (256x256): [[Wr,-Wi],[Wi,Wr]] fold of mixed 256x128 w_m1
        int i3 = tid - 296448;
        int b = i3 >> 16, rem = i3 & 65535;
        int o = rem >> 8, i = rem & 255;
        int r, cc; float sign = 1.0f;
        if (o < 128) { if (i < 128) { r = o;       cc = i; } else { r = 128 + o;      cc = i - 128; sign = -1.0f; } }
        else { int o2 = o - 128; if (i < 128) { r = 128 + o2; cc = i; } else { r = o2; cc = i - 128; } }
        int idx = r * 128 + cc;
        float s = ws_m1[idx];
        #pragma unroll
        for (int e = 0; e < 8; e++) s += coef[b * 8 + e] * w_m1[e * 32768 + idx];
        W1[i3] = f2bf(sign * s);
    } else if (tid < 951808) {
        int i4 = tid - 820736;
        int b = i4 >> 14, rem = i4 & 16383;
        int o = rem >> 7, i = rem & 127;
        int r, cc; float sign = 1.0f;
        if (o < 64) { if (i < 64) { r = o;      cc = i; } else { r = 64 + o;      cc = i - 64; sign = -1.0f; } }
        else { int o2 = o - 64; if (i < 64) { r = 64 + o2; cc = i; } else { r = o2; cc = i - 64; } }
        int idx = r * 64 + cc;
        float s = ws_m2[idx];
        #pragma unroll
        for (int e = 0; e < 8; e++) s += coef[b * 8 + e] * w_m2[e * 8192 + idx];
        W2[i4] = f2bf(sign * s);
    }
}

// ---------------- rotation helpers ----------------
__device__ __forceinline__ void zrot1(float& v0, float& v2, float c, float s) {
    float t0 = c * v0 + s * v2;
    v2 = -s * v0 + c * v2;
    v0 = t0;
}
__device__ __forceinline__ void j1mul(const float* J, float& v0, float& v1, float& v2) {
    float w0 = J[0] * v0 + J[1] * v1 + J[2] * v2;
    float w1 = J[3] * v0 + J[4] * v1 + J[5] * v2;
    float w2 = J[6] * v0 + J[7] * v1 + J[8] * v2;
    v0 = w0; v1 = w1; v2 = w2;
}
__device__ __forceinline__ void zrot2(float& u0, float& u1, float& u3, float& u4,
                                      float c1, float s1, float c2, float s2) {
    float t0 = c2 * u0 + s2 * u4;
    u4 = -s2 * u0 + c2 * u4;
    u0 = t0;
    float t1 = c1 * u1 + s1 * u3;
    u3 = -s1 * u1 + c1 * u3;
    u1 = t1;
}
__device__ __forceinline__ void j2mul(const float* J, float& u0, float& u1, float& u2, float& u3, float& u4) {
    float w0 = J[0]  * u0 + J[1]  * u1 + J[2]  * u2 + J[3]  * u3 + J[4]  * u4;
    float w1 = J[5]  * u0 + J[6]  * u1 + J[7]  * u2 + J[8]  * u3 + J[9]  * u4;
    float w2 = J[10] * u0 + J[11] * u1 + J[12] * u2 + J[13] * u3 + J[14] * u4;
    float w3 = J[15] * u0 + J[16] * u1 + J[17] * u2 + J[18] * u3 + J[19] * u4;
    float w4 = J[20] * u0 + J[21] * u1 + J[22] * u2 + J[23] * u3 + J[24] * u4;
    u0 = w0; u1 = w1; u2 = w2; u3 = w3; u4 = w4;
}

// ---------------- forward rotate + gather to bf16 GEMM layouts ----------------
__global__ __launch_bounds__(256) void rotate_fwd(
    const float* __restrict__ x,
    const float* __restrict__ alpha, const float* __restrict__ beta, const float* __restrict__ gamma_,
    const float* __restrict__ Jd1, const float* __restrict__ Jd2,
    ushort_t* __restrict__ X0, ushort_t* __restrict__ X1, ushort_t* __restrict__ X2)
{
    int t = threadIdx.x;
    int n = blockIdx.x * 4 + (t >> 6);
    int c = t & 63;
    const float* xr = x + (size_t)n * 576;
    float a = alpha[n], b = beta[n], g = gamma_[n];
    float sa, ca, sb, cb, sg, cg;
    __sincosf(a, &sa, &ca);
    __sincosf(b, &sb, &cb);
    __sincosf(g, &sg, &cg);
    float s2a = 2.f * sa * ca, c2a = ca * ca - sa * sa;
    float s2b = 2.f * sb * cb, c2b = cb * cb - sb * sb;
    float s2g = 2.f * sg * cg, c2g = cg * cg - sg * sg;

    float J1[9], J2[25];
    #pragma unroll
    for (int i = 0; i < 9; i++)  J1[i] = Jd1[i];
    #pragma unroll
    for (int i = 0; i < 25; i++) J2[i] = Jd2[i];

    float v0 = xr[64 + 3 * c], v1 = xr[64 + 3 * c + 1], v2 = xr[64 + 3 * c + 2];
    zrot1(v0, v2, cg, sg);
    j1mul(J1, v0, v1, v2);
    zrot1(v0, v2, cb, sb);
    j1mul(J1, v0, v1, v2);
    zrot1(v0, v2, ca, sa);

    float u0 = xr[256 + 5 * c], u1 = xr[256 + 5 * c + 1], u2 = xr[256 + 5 * c + 2],
          u3 = xr[256 + 5 * c + 3], u4 = xr[256 + 5 * c + 4];
    zrot2(u0, u1, u3, u4, cg, sg, c2g, s2g);
    j2mul(J2, u0, u1, u2, u3, u4);
    zrot2(u0, u1, u3, u4, cb, sb, c2b, s2b);
    j2mul(J2, u0, u1, u2, u3, u4);
    zrot2(u0, u1, u3, u4, ca, sa, c2a, s2a);

    size_t row = grow(n);
    size_t r0 = row * 192, r1 = row * 256, r2 = row * 128;
    X0[r0 + c]       = f2bf(xr[c]);
    X0[r0 + 64 + c]  = f2bf(v1);
    X0[r0 + 128 + c] = f2bf(u2);
    X1[r1 + c]       = f2bf(v0);
    X1[r1 + 64 + c]  = f2bf(u1);
    X1[r1 + 128 + c] = f2bf(v2);
    X1[r1 + 192 + c] = f2bf(u3);
    X2[r2 + c]       = f2bf(u0);
    X2[r2 + 64 + c]  = f2bf(u4);
}

// ---------------- bf16 MFMA GEMM: Y[m,n] = sum_k X[m,k] W[n,k] (+bias[n]) ----------------
// D = K = N of this GEMM. BM=128 fixed, BN in {64,128}. 4 waves in 2x2.
// grid: (D/BN, 8 groups * 64 mtiles)
template<int D, int BN, bool BIAS>
__global__ __launch_bounds__(256) void mfma_gemm(
    const ushort_t* __restrict__ X, const ushort_t* __restrict__ W,
    const float* __restrict__ bias, float* __restrict__ Y)
{
    constexpr int AG = 512;           // A 16B-granules: 128 rows * 4
    constexpr int BG = BN * 4;
    constexpr int TG = AG + BG;       // 768 or 1024 -> uniform staging
    constexpr int NT = BN / 32;       // MFMA n-tiles per wave

    __shared__ ushort_t As[128 * 32];
    __shared__ ushort_t Bs[BN * 32];

    int t = threadIdx.x;
    int g = blockIdx.y >> 6;
    int tm = blockIdx.y & 63;
    int n0 = blockIdx.x * BN;

    const ushort_t* Xb = X + ((size_t)g * GPAD + (size_t)tm * 128) * D;
    const ushort_t* Wg = W + (size_t)g * D * D + (size_t)n0 * D;
    float* Yb = Y + ((size_t)g * GPAD + (size_t)tm * 128) * D + n0;

    int lane = t & 63;
    int w = t >> 6;
    int wm = w & 1, wn = w >> 1;
    int mi = lane & 15;
    int quad = lane >> 4;
    int qa = quad ^ ((mi >> 1) & 3);  // XOR-swizzled k-granule for frag reads

    floatx4 acc[4][NT];
    #pragma unroll
    for (int i = 0; i < 4; i++)
        #pragma unroll
        for (int j = 0; j < NT; j++) acc[i][j] = (floatx4)0.f;

    #pragma unroll
    for (int k0 = 0; k0 < D; k0 += 32) {
        __syncthreads();
        #pragma unroll
        for (int it = 0; it < TG / 256; ++it) {
            int gi = it * 256 + t;
            if (gi < AG) {
                int row = gi >> 2;
                int q = (gi & 3) ^ ((row >> 1) & 3);
                async_cp16(Xb + (size_t)row * D + k0 + q * 8, &As[gi * 8]);
            } else {
                int gj = gi - AG;
                int row = gj >> 2;
                int q = (gj & 3) ^ ((row >> 1) & 3);
                async_cp16(Wg + (size_t)row * D + k0 + q * 8, &Bs[gj * 8]);
            }
        }
        __syncthreads();

        bf16x8 af[4], bfr[NT];
        #pragma unroll
        for (int i = 0; i < 4; i++) {
            int row = wm * 64 + i * 16 + mi;
            af[i] = *(const bf16x8*)&As[row * 32 + qa * 8];
        }
        #pragma unroll
        for (int j = 0; j < NT; j++) {
            int row = wn * (BN / 2) + j * 16 + mi;
            bfr[j] = *(const bf16x8*)&Bs[row * 32 + qa * 8];
        }
        #pragma unroll
        for (int i = 0; i < 4; i++)
            #pragma unroll
            for (int j = 0; j < NT; j++)
                acc[i][j] = __builtin_amdgcn_mfma_f32_16x16x32_bf16(af[i], bfr[j], acc[i][j], 0, 0, 0);
    }

    // epilogue: D element (m = quad*4+r, n = mi) within each 16x16 tile
    #pragma unroll
    for (int j = 0; j < NT; j++) {
        int col = wn * (BN / 2) + j * 16 + mi;
        float bv = 0.f;
        if (BIAS) bv = bias[g * D + n0 + col];
        #pragma unroll
        for (int i = 0; i < 4; i++) {
            int rbase = wm * 64 + i * 16 + quad * 4;
            #pragma unroll
            for (int r = 0; r < 4; r++) {
                Yb[(size_t)(rbase + r) * D + col] = acc[i][j][r] + bv;
            }
        }
    }
}

// ---------------- inverse rotate + scatter to output ----------------
__global__ __launch_bounds__(256) void rotate_bwd(
    const float* __restrict__ Y0, const float* __restrict__ Y1, const float* __restrict__ Y2,
    const float* __restrict__ alpha, const float* __restrict__ beta, const float* __restrict__ gamma_,
    const float* __restrict__ Jd1, const float* __restrict__ Jd2,
    float* __restrict__ out)
{
    int t = threadIdx.x;
    int n = blockIdx.x * 4 + (t >> 6);
    int c = t & 63;
    float a = alpha[n], b = beta[n], g = gamma_[n];
    float sa, ca, sb, cb, sg, cg;
    __sincosf(a, &sa, &ca);
    __sincosf(b, &sb, &cb);
    __sincosf(g, &sg, &cg);
    sa = -sa; sb = -sb; sg = -sg;    // inverse angles
    float s2a = 2.f * sa * ca, c2a = ca * ca - sa * sa;
    float s2b = 2.f * sb * cb, c2b = cb * cb - sb * sb;
    float s2g = 2.f * sg * cg, c2g = cg * cg - sg * sg;

    float J1[9], J2[25];
    #pragma unroll
    for (int i = 0; i < 9; i++)  J1[i] = Jd1[i];
    #pragma unroll
    for (int i = 0; i < 25; i++) J2[i] = Jd2[i];

    size_t row = grow(n);
    size_t r0 = row * 192, r1 = row * 256, r2 = row * 128;
    float* orow = out + (size_t)n * 576;

    orow[c] = Y0[r0 + c];

    float v0 = Y1[r1 + c], v1 = Y0[r0 + 64 + c], v2 = Y1[r1 + 128 + c];
    zrot1(v0, v2, ca, sa);
    j1mul(J1, v0, v1, v2);
    zrot1(v0, v2, cb, sb);
    j1mul(J1, v0, v1, v2);
    zrot1(v0, v2, cg, sg);
    orow[64 + 3 * c]     = v0;
    orow[64 + 3 * c + 1] = v1;
    orow[64 + 3 * c + 2] = v2;

    float u0 = Y2[r2 + c], u1 = Y1[r1 + 64 + c], u2 = Y0[r0 + 128 + c],
          u3 = Y1[r1 + 192 + c], u4 = Y2[r2 + 64 + c];
    zrot2(u0, u1, u3, u4, ca, sa, c2a, s2a);
    j2mul(J2, u0, u1, u2, u3, u4);
    zrot2(u0, u1, u3, u4, cb, sb, c2b, s2b);
    j2mul(J2, u0, u1, u2, u3, u4);
    zrot2(u0, u1, u3, u4, cg, sg, c2g, s2g);
    orow[256 + 5 * c]     = u0;
    orow[256 + 5 * c + 1] = u1;
    orow[256 + 5 * c + 2] = u2;
    orow[256 + 5 * c + 3] = u3;
    orow[256 + 5 * c + 4] = u4;
}

extern "C" void kernel_launch(void* const* d_in, const int* in_sizes, int n_in,
                              void* d_out, int out_size, void* d_ws, size_t ws_size,
                              hipStream_t stream)
{
    const float* x      = (const float*)d_in[0];
    const float* alpha  = (const float*)d_in[1];
    const float* beta   = (const float*)d_in[2];
    const float* gamma_ = (const float*)d_in[3];
    const float* coef   = (const float*)d_in[4];
    const float* Jd1    = (const float*)d_in[5];
    const float* Jd2    = (const float*)d_in[6];
    const float* w_m0   = (const float*)d_in[7];
    const float* b_m0   = (const float*)d_in[8];
    const float* ws_m0  = (const float*)d_in[9];
    const float* bs_m0  = (const float*)d_in[10];
    const float* w_m1   = (const float*)d_in[11];
    const float* ws_m1  = (const float*)d_in[12];
    const float* w_m2   = (const float*)d_in[13];
    const float* ws_m2  = (const float*)d_in[14];

    char* wsb = (char*)d_ws;
    ushort_t* W0 = (ushort_t*)(wsb + BY_W0);
    ushort_t* W1 = (ushort_t*)(wsb + BY_W1);
    ushort_t* W2 = (ushort_t*)(wsb + BY_W2);
    float*    B0 = (float*)(wsb + BY_B0);
    ushort_t* X0 = (ushort_t*)(wsb + BY_X0);
    ushort_t* X1 = (ushort_t*)(wsb + BY_X1);
    ushort_t* X2 = (ushort_t*)(wsb + BY_X2);
    float*    Y0 = (float*)(wsb + BY_Y0);
    float*    Y1 = (float*)(wsb + BY_Y1);
    float*    Y2 = (float*)(wsb + BY_Y2);
    float*    out = (float*)d_out;

    hipLaunchKernelGGL(mix_kernel, dim3(3718), dim3(256), 0, stream,
                       coef, w_m0, b_m0, ws_m0, bs_m0, w_m1, ws_m1, w_m2, ws_m2,
                       W0, B0, W1, W2);
    hipLaunchKernelGGL(rotate_fwd, dim3(NS / 4), dim3(256), 0, stream,
                       x, alpha, beta, gamma_, Jd1, Jd2, X0, X1, X2);
    hipLaunchKernelGGL((mfma_gemm<192, 64, true>),  dim3(3, 512), dim3(256), 0, stream, X0, W0, B0, Y0);
    hipLaunchKernelGGL((mfma_gemm<256, 128, false>), dim3(2, 512), dim3(256), 0, stream, X1, W1, (const float*)nullptr, Y1);
    hipLaunchKernelGGL((mfma_gemm<128, 128, false>), dim3(1, 512), dim3(256), 0, stream, X2, W2, (const float*)nullptr, Y2);
    hipLaunchKernelGGL(rotate_bwd, dim3(NS / 4), dim3(256), 0, stream,
                       Y0, Y1, Y2, alpha, beta, gamma_, Jd1, Jd2, out);
}

// Round 3
// 337.915 us; speedup vs baseline: 1.6695x; 1.1747x over previous
//
#include <hip/hip_runtime.h>
#include <cstddef>

#define NS 64000
#define GROUP 8000
#define TM 64

typedef __bf16 bf16x8 __attribute__((ext_vector_type(8)));
typedef float floatx4 __attribute__((ext_vector_type(4)));
typedef unsigned short ushort_t;

// ---------------- ws layout (bytes): only mixed weights now ----------------
static const size_t BY_W0 = 0;                      // 8*192*192*2 = 589824
static const size_t BY_W1 = BY_W0 + 589824;         // 8*256*256*2 = 1048576
static const size_t BY_W2 = BY_W1 + 1048576;        // 8*128*128*2 = 262144
static const size_t BY_B0 = BY_W2 + 262144;         // 8*192*4     = 6144

__device__ __forceinline__ unsigned short f2bf(float f) {
    unsigned u = __float_as_uint(f);
    u += 0x7fff + ((u >> 16) & 1);   // RNE
    return (unsigned short)(u >> 16);
}

// ---------------- expert-mix kernel (bf16 weights out) ----------------
__global__ __launch_bounds__(256) void mix_kernel(
    const float* __restrict__ coef,
    const float* __restrict__ w_m0, const float* __restrict__ b_m0,
    const float* __restrict__ ws_m0, const float* __restrict__ bs_m0,
    const float* __restrict__ w_m1, const float* __restrict__ ws_m1,
    const float* __restrict__ w_m2, const float* __restrict__ ws_m2,
    ushort_t* __restrict__ W0, float* __restrict__ B0,
    ushort_t* __restrict__ W1, ushort_t* __restrict__ W2)
{
    int tid = blockIdx.x * 256 + threadIdx.x;
    if (tid < 294912) {
        int b = tid / 36864, rem = tid % 36864;
        float s = ws_m0[rem];
        #pragma unroll
        for (int e = 0; e < 8; e++) s += coef[b * 8 + e] * w_m0[e * 36864 + rem];
        W0[tid] = f2bf(s);
    } else if (tid < 296448) {
        int i2 = tid - 294912;
        int b = i2 / 192, o = i2 % 192;
        float s = bs_m0[o];
        #pragma unroll
        for (int e = 0; e < 8; e++) s += coef[b * 8 + e] * b_m0[e * 192 + o];
        B0[i2] = s;
    } else if (tid < 820736) {
        // W1big[b,o,i] (256x256): [[Wr,-Wi],[Wi,Wr]] fold of mixed 256x128 w_m1
        int i3 = tid - 296448;
        int b = i3 >> 16, rem = i3 & 65535;
        int o = rem >> 8, i = rem & 255;
        int r, cc; float sign = 1.0f;
        if (o < 128) { if (i < 128) { r = o;       cc = i; } else { r = 128 + o;      cc = i - 128; sign = -1.0f; } }
        else { int o2 = o - 128; if (i < 128) { r = 128 + o2; cc = i; } else { r = o2; cc = i - 128; } }
        int idx = r * 128 + cc;
        float s = ws_m1[idx];
        #pragma unroll
        for (int e = 0; e < 8; e++) s += coef[b * 8 + e] * w_m1[e * 32768 + idx];
        W1[i3] = f2bf(sign * s);
    } else if (tid < 951808) {
        int i4 = tid - 820736;
        int b = i4 >> 14, rem = i4 & 16383;
        int o = rem >> 7, i = rem & 127;
        int r, cc; float sign = 1.0f;
        if (o < 64) { if (i < 64) { r = o;      cc = i; } else { r = 64 + o;      cc = i - 64; sign = -1.0f; } }
        else { int o2 = o - 64; if (i < 64) { r = 64 + o2; cc = i; } else { r = o2; cc = i - 64; } }
        int idx = r * 64 + cc;
        float s = ws_m2[idx];
        #pragma unroll
        for (int e = 0; e < 8; e++) s += coef[b * 8 + e] * w_m2[e * 8192 + idx];
        W2[i4] = f2bf(sign * s);
    }
}

// ---------------- rotation helpers ----------------
__device__ __forceinline__ void zrot1(float& v0, float& v2, float c, float s) {
    float t0 = c * v0 + s * v2;
    v2 = -s * v0 + c * v2;
    v0 = t0;
}
__device__ __forceinline__ void j1mul(const float* J, float& v0, float& v1, float& v2) {
    float w0 = J[0] * v0 + J[1] * v1 + J[2] * v2;
    float w1 = J[3] * v0 + J[4] * v1 + J[5] * v2;
    float w2 = J[6] * v0 + J[7] * v1 + J[8] * v2;
    v0 = w0; v1 = w1; v2 = w2;
}
__device__ __forceinline__ void zrot2(float& u0, float& u1, float& u3, float& u4,
                                      float c1, float s1, float c2, float s2) {
    float t0 = c2 * u0 + s2 * u4;
    u4 = -s2 * u0 + c2 * u4;
    u0 = t0;
    float t1 = c1 * u1 + s1 * u3;
    u3 = -s1 * u1 + c1 * u3;
    u1 = t1;
}
__device__ __forceinline__ void j2mul(const float* J, float& u0, float& u1, float& u2, float& u3, float& u4) {
    float w0 = J[0]  * u0 + J[1]  * u1 + J[2]  * u2 + J[3]  * u3 + J[4]  * u4;
    float w1 = J[5]  * u0 + J[6]  * u1 + J[7]  * u2 + J[8]  * u3 + J[9]  * u4;
    float w2 = J[10] * u0 + J[11] * u1 + J[12] * u2 + J[13] * u3 + J[14] * u4;
    float w3 = J[15] * u0 + J[16] * u1 + J[17] * u2 + J[18] * u3 + J[19] * u4;
    float w4 = J[20] * u0 + J[21] * u1 + J[22] * u2 + J[23] * u3 + J[24] * u4;
    u0 = w0; u1 = w1; u2 = w2; u3 = w3; u4 = w4;
}

// swizzled LDS element index: row-major [row][K], 16B granules XOR'd by row&7.
// valid since K/8 is a multiple of 8 for K in {128,192,256}.
__device__ __forceinline__ int sidx(int row, int k, int K) {
    int gr = (k >> 3) ^ (row & 7);
    return row * K + gr * 8 + (k & 7);
}
__device__ __forceinline__ float yread(const ushort_t* L, int row, int k, int K) {
    unsigned u = L[sidx(row, k, K)];
    return __uint_as_float(u << 16);
}

// ---------------- per-wave GEMM segment: acc[t][ms] += X(LDS) * Wseg(rows t*16+mi) ----------------
template<int K, int NT>
__device__ __forceinline__ void gemm_seg(
    floatx4 (*acc)[4],
    const ushort_t* __restrict__ Wseg,   // global (L2-resident), row-major, length-K rows
    const ushort_t* XL_,                 // LDS region, swizzled
    int mi, int quad)
{
    #pragma unroll
    for (int k0 = 0; k0 < K; k0 += 32) {
        bf16x8 af[4];
        #pragma unroll
        for (int ms = 0; ms < 4; ms++) {
            int row = ms * 16 + mi;
            int gr = ((k0 >> 3) + quad) ^ (row & 7);
            af[ms] = *(const bf16x8*)&XL_[row * K + gr * 8];
        }
        bf16x8 bfr[NT];
        #pragma unroll
        for (int t = 0; t < NT; t++)
            bfr[t] = *(const bf16x8*)&Wseg[(size_t)(t * 16 + mi) * K + k0 + quad * 8];
        #pragma unroll
        for (int t = 0; t < NT; t++)
            #pragma unroll
            for (int ms = 0; ms < 4; ms++)
                acc[t][ms] = __builtin_amdgcn_mfma_f32_16x16x32_bf16(af[ms], bfr[t], acc[t][ms], 0, 0, 0);
    }
}

// write acc tiles into LDS Y (bf16, same swizzled layout), optional bias add
template<int K, int NT, bool BIAS>
__device__ __forceinline__ void ywrite(
    floatx4 (*acc)[4], ushort_t* L, int n0, const float* __restrict__ bias,
    int mi, int quad)
{
    #pragma unroll
    for (int t = 0; t < NT; t++) {
        int col = n0 + t * 16 + mi;
        float bv = BIAS ? bias[col] : 0.f;
        int gc = col >> 3, kw = col & 7;
        #pragma unroll
        for (int ms = 0; ms < 4; ms++) {
            #pragma unroll
            for (int r = 0; r < 4; r++) {
                int m = ms * 16 + quad * 4 + r;
                L[m * K + ((gc ^ (m & 7)) * 8) + kw] = f2bf(acc[t][ms][r] + bv);
            }
        }
    }
}

// ---------------- fused: rotate -> 3 GEMMs -> inverse rotate ----------------
__global__ __launch_bounds__(256, 2) void fused_kernel(
    const float* __restrict__ x,
    const float* __restrict__ alpha, const float* __restrict__ beta, const float* __restrict__ gamma_,
    const float* __restrict__ Jd1, const float* __restrict__ Jd2,
    const ushort_t* __restrict__ W0, const ushort_t* __restrict__ W1, const ushort_t* __restrict__ W2,
    const float* __restrict__ B0,
    float* __restrict__ out)
{
    __shared__ ushort_t XL[36864];   // X then Y: X0(64x192) | X1(64x256) | X2(64x128)
    __shared__ float TR[64 * 6];
    __shared__ float JL[34];

    ushort_t* X0L = XL;
    ushort_t* X1L = XL + 12288;
    ushort_t* X2L = XL + 28672;

    int t = threadIdx.x;
    int w = t >> 6, lane = t & 63;
    int g = blockIdx.x / 125;
    int base = g * GROUP + (blockIdx.x % 125) * TM;

    if (t < 64) {
        int n = base + t;
        float sa, ca, sb, cb, sg, cg;
        __sincosf(alpha[n],  &sa, &ca);
        __sincosf(beta[n],   &sb, &cb);
        __sincosf(gamma_[n], &sg, &cg);
        TR[t * 6 + 0] = sa; TR[t * 6 + 1] = ca;
        TR[t * 6 + 2] = sb; TR[t * 6 + 3] = cb;
        TR[t * 6 + 4] = sg; TR[t * 6 + 5] = cg;
    } else if (t < 98) {
        int j = t - 64;
        JL[j] = (j < 9) ? Jd1[j] : Jd2[j - 9];
    }
    __syncthreads();

    const float* J1 = JL;
    const float* J2 = JL + 9;
    int c = lane;

    // ---- phase A: forward rotate x -> LDS bf16 ----
    for (int i = 0; i < 16; i++) {
        int nl = w * 16 + i;
        const float* xr = x + (size_t)(base + nl) * 576;
        float sa = TR[nl * 6 + 0], ca = TR[nl * 6 + 1];
        float sb = TR[nl * 6 + 2], cb = TR[nl * 6 + 3];
        float sg = TR[nl * 6 + 4], cg = TR[nl * 6 + 5];
        float s2a = 2.f * sa * ca, c2a = ca * ca - sa * sa;
        float s2b = 2.f * sb * cb, c2b = cb * cb - sb * sb;
        float s2g = 2.f * sg * cg, c2g = cg * cg - sg * sg;

        float v0 = xr[64 + 3 * c], v1 = xr[64 + 3 * c + 1], v2 = xr[64 + 3 * c + 2];
        zrot1(v0, v2, cg, sg);
        j1mul(J1, v0, v1, v2);
        zrot1(v0, v2, cb, sb);
        j1mul(J1, v0, v1, v2);
        zrot1(v0, v2, ca, sa);

        float u0 = xr[256 + 5 * c], u1 = xr[256 + 5 * c + 1], u2 = xr[256 + 5 * c + 2],
              u3 = xr[256 + 5 * c + 3], u4 = xr[256 + 5 * c + 4];
        zrot2(u0, u1, u3, u4, cg, sg, c2g, s2g);
        j2mul(J2, u0, u1, u2, u3, u4);
        zrot2(u0, u1, u3, u4, cb, sb, c2b, s2b);
        j2mul(J2, u0, u1, u2, u3, u4);
        zrot2(u0, u1, u3, u4, ca, sa, c2a, s2a);

        X0L[sidx(nl, c, 192)]       = f2bf(xr[c]);
        X0L[sidx(nl, 64 + c, 192)]  = f2bf(v1);
        X0L[sidx(nl, 128 + c, 192)] = f2bf(u2);
        X1L[sidx(nl, c, 256)]       = f2bf(v0);
        X1L[sidx(nl, 64 + c, 256)]  = f2bf(u1);
        X1L[sidx(nl, 128 + c, 256)] = f2bf(v2);
        X1L[sidx(nl, 192 + c, 256)] = f2bf(u3);
        X2L[sidx(nl, c, 128)]       = f2bf(u0);
        X2L[sidx(nl, 64 + c, 128)]  = f2bf(u4);
    }
    __syncthreads();

    // ---- phase B: MFMA GEMMs, B-fragments streamed from L2 ----
    int mi = lane & 15, quad = lane >> 4;
    floatx4 acc[10][4];
    #pragma unroll
    for (int a = 0; a < 10; a++)
        #pragma unroll
        for (int b2 = 0; b2 < 4; b2++) acc[a][b2] = (floatx4)0.f;

    const ushort_t* W0g = W0 + (size_t)g * 192 * 192;
    const ushort_t* W1g = W1 + (size_t)g * 256 * 256;
    const ushort_t* W2g = W2 + (size_t)g * 128 * 128;

    if (w == 0) {
        gemm_seg<192, 10>(acc, W0g, X0L, mi, quad);                       // Y0 cols 0..159
    } else if (w == 1) {
        gemm_seg<256, 8>(acc, W1g, X1L, mi, quad);                        // Y1 cols 0..127
    } else if (w == 2) {
        gemm_seg<256, 8>(acc, W1g + (size_t)128 * 256, X1L, mi, quad);    // Y1 cols 128..255
    } else {
        gemm_seg<192, 2>(acc, W0g + (size_t)160 * 192, X0L, mi, quad);    // Y0 cols 160..191
        gemm_seg<128, 8>(acc + 2, W2g, X2L, mi, quad);                    // Y2 cols 0..127
    }

    __syncthreads();   // everyone done reading X from LDS

    const float* B0g = B0 + g * 192;
    if (w == 0) {
        ywrite<192, 10, true>(acc, X0L, 0, B0g, mi, quad);
    } else if (w == 1) {
        ywrite<256, 8, false>(acc, X1L, 0, nullptr, mi, quad);
    } else if (w == 2) {
        ywrite<256, 8, false>(acc, X1L, 128, nullptr, mi, quad);
    } else {
        ywrite<192, 2, true>(acc, X0L, 160, B0g, mi, quad);
        ywrite<128, 8, false>(acc + 2, X2L, 0, nullptr, mi, quad);
    }
    __syncthreads();

    // ---- phase C: inverse rotate Y(LDS) -> out ----
    for (int i = 0; i < 16; i++) {
        int nl = w * 16 + i;
        float sa = -TR[nl * 6 + 0], ca = TR[nl * 6 + 1];
        float sb = -TR[nl * 6 + 2], cb = TR[nl * 6 + 3];
        float sg = -TR[nl * 6 + 4], cg = TR[nl * 6 + 5];
        float s2a = 2.f * sa * ca, c2a = ca * ca - sa * sa;
        float s2b = 2.f * sb * cb, c2b = cb * cb - sb * sb;
        float s2g = 2.f * sg * cg, c2g = cg * cg - sg * sg;

        float* orow = out + (size_t)(base + nl) * 576;

        orow[c] = yread(X0L, nl, c, 192);

        float v0 = yread(X1L, nl, c, 256);
        float v1 = yread(X0L, nl, 64 + c, 192);
        float v2 = yread(X1L, nl, 128 + c, 256);
        zrot1(v0, v2, ca, sa);
        j1mul(J1, v0, v1, v2);
        zrot1(v0, v2, cb, sb);
        j1mul(J1, v0, v1, v2);
        zrot1(v0, v2, cg, sg);
        orow[64 + 3 * c]     = v0;
        orow[64 + 3 * c + 1] = v1;
        orow[64 + 3 * c + 2] = v2;

        float u0 = yread(X2L, nl, c, 128);
        float u1 = yread(X1L, nl, 64 + c, 256);
        float u2 = yread(X0L, nl, 128 + c, 192);
        float u3 = yread(X1L, nl, 192 + c, 256);
        float u4 = yread(X2L, nl, 64 + c, 128);
        zrot2(u0, u1, u3, u4, ca, sa, c2a, s2a);
        j2mul(J2, u0, u1, u2, u3, u4);
        zrot2(u0, u1, u3, u4, cb, sb, c2b, s2b);
        j2mul(J2, u0, u1, u2, u3, u4);
        zrot2(u0, u1, u3, u4, cg, sg, c2g, s2g);
        orow[256 + 5 * c]     = u0;
        orow[256 + 5 * c + 1] = u1;
        orow[256 + 5 * c + 2] = u2;
        orow[256 + 5 * c + 3] = u3;
        orow[256 + 5 * c + 4] = u4;
    }
}

extern "C" void kernel_launch(void* const* d_in, const int* in_sizes, int n_in,
                              void* d_out, int out_size, void* d_ws, size_t ws_size,
                              hipStream_t stream)
{
    const float* x      = (const float*)d_in[0];
    const float* alpha  = (const float*)d_in[1];
    const float* beta   = (const float*)d_in[2];
    const float* gamma_ = (const float*)d_in[3];
    const float* coef   = (const float*)d_in[4];
    const float* Jd1    = (const float*)d_in[5];
    const float* Jd2    = (const float*)d_in[6];
    const float* w_m0   = (const float*)d_in[7];
    const float* b_m0   = (const float*)d_in[8];
    const float* ws_m0  = (const float*)d_in[9];
    const float* bs_m0  = (const float*)d_in[10];
    const float* w_m1   = (const float*)d_in[11];
    const float* ws_m1  = (const float*)d_in[12];
    const float* w_m2   = (const float*)d_in[13];
    const float* ws_m2  = (const float*)d_in[14];

    char* wsb = (char*)d_ws;
    ushort_t* W0 = (ushort_t*)(wsb + BY_W0);
    ushort_t* W1 = (ushort_t*)(wsb + BY_W1);
    ushort_t* W2 = (ushort_t*)(wsb + BY_W2);
    float*    B0 = (float*)(wsb + BY_B0);
    float*    out = (float*)d_out;

    hipLaunchKernelGGL(mix_kernel, dim3(3718), dim3(256), 0, stream,
                       coef, w_m0, b_m0, ws_m0, bs_m0, w_m1, ws_m1, w_m2, ws_m2,
                       W0, B0, W1, W2);
    hipLaunchKernelGGL(fused_kernel, dim3(1000), dim3(256), 0, stream,
                       x, alpha, beta, gamma_, Jd1, Jd2, W0, W1, W2, B0, out);
}